// Round 2
// baseline (255.796 us; speedup 1.0000x reference)
//
#include <hip/hip_runtime.h>
#include <hip/hip_bf16.h>

// out[b, c, i, j] = x[b, c, i, j] + pe_flat[g],  g = c*4096 + i*64 + j (flat idx per batch)
// pe_flat is the [H=64, W=64, C=256] pe tensor viewed flat (reference's raw reshape):
//   c2 = g & 255, j2 = (g >> 8) & 63, i2 = (g >> 14) & 63
//   pe = jj*(W0-W2) + ii*(W1-W3) + (W2+W3+b),   jj = j2/63, ii = i2/63
// pe is batch-independent. Grid stride = 2^20 float4 = exactly 4 batches, so each
// thread's within-batch position is loop-invariant -> pe computed once in registers.
//
// R6: discriminating experiment. Drop ALL exotic paths and mimic the proven
// m13 float4-copy recipe exactly: plain grid-stride loop, normal global loads
// and stores, compiler-scheduled. m13 proves this structure sustains 6.29 TB/s
// on gfx950. If dur_us doesn't move vs R4/R5, the kernel is already at the
// memory roofline and the 235 µs floor is harness poison-fill + dispatch
// overhead (2x79 µs fills of 512 MiB each dominate the timed region).

typedef float vf4 __attribute__((ext_vector_type(4)));

#define TOTAL_F4   (1u << 23)        // 32*256*64*64 floats / 4
#define THREADS    256
#define BLOCKS     4096              // 2^20 threads total
#define STRIDE_F4  (1u << 20)        // BLOCKS*THREADS; = 4 batches worth of float4
#define ITERS      8                 // TOTAL_F4 / STRIDE_F4

__global__ __launch_bounds__(THREADS) void pe_add_kernel(
    const float* __restrict__ x,
    const float* __restrict__ Wm,    // [256, 4] row-major
    const float* __restrict__ bias,  // [256]
    float* __restrict__ out)
{
    const unsigned t = blockIdx.x * (unsigned)THREADS + threadIdx.x;   // [0, 2^20)

    // Within-batch position (invariant across iterations: stride = 4 batches).
    const unsigned p  = t & ((1u << 18) - 1u);   // float4 index within a batch
    const unsigned g  = p << 2;                  // element index within a batch
    const unsigned c2 = g & 255u;                // channel of first element (multiple of 4)
    const unsigned j2 = (g >> 8) & 63u;
    const unsigned i2 = (g >> 14) & 63u;

    const float u = (float)j2 * (1.0f / 63.0f);
    const float v = (float)i2 * (1.0f / 63.0f);

    // W rows c2 .. c2+3 and bias[c2..c2+3]: aligned 16B loads, L1/L2-hot.
    const vf4* Wrows = reinterpret_cast<const vf4*>(Wm);
    const vf4 wa = Wrows[c2 + 0];
    const vf4 wb = Wrows[c2 + 1];
    const vf4 wc = Wrows[c2 + 2];
    const vf4 wd = Wrows[c2 + 3];
    const vf4 bv = reinterpret_cast<const vf4*>(bias)[c2 >> 2];

    const vf4 pe = {
        u * (wa.x - wa.z) + v * (wa.y - wa.w) + (wa.z + wa.w + bv.x),
        u * (wb.x - wb.z) + v * (wb.y - wb.w) + (wb.z + wb.w + bv.y),
        u * (wc.x - wc.z) + v * (wc.y - wc.w) + (wc.z + wc.w + bv.z),
        u * (wd.x - wd.z) + v * (wd.y - wd.w) + (wd.z + wd.w + bv.w),
    };

    const vf4* xp = reinterpret_cast<const vf4*>(x);
    vf4*       op = reinterpret_cast<vf4*>(out);

    // Proven copy structure: load-add-store per step, normal memory ops,
    // compiler free to schedule/pipeline the unrolled body.
#pragma unroll
    for (unsigned n = 0; n < ITERS; ++n) {
        const size_t f = (size_t)t + (size_t)n * STRIDE_F4;
        op[f] = xp[f] + pe;
    }
}

extern "C" void kernel_launch(void* const* d_in, const int* in_sizes, int n_in,
                              void* d_out, int out_size, void* d_ws, size_t ws_size,
                              hipStream_t stream) {
    const float* x    = (const float*)d_in[0];  // [32, 256, 64, 64] fp32
    const float* Wm   = (const float*)d_in[1];  // [256, 4] fp32
    const float* bias = (const float*)d_in[2];  // [256] fp32
    float* out = (float*)d_out;                 // [32, 256, 64, 64] fp32

    pe_add_kernel<<<dim3(BLOCKS), dim3(THREADS), 0, stream>>>(x, Wm, bias, out);
}

// Round 3
// 245.052 us; speedup vs baseline: 1.0438x; 1.0438x over previous
//
#include <hip/hip_runtime.h>
#include <hip/hip_bf16.h>

// out[b, c, i, j] = x[b, c, i, j] + pe_flat[g],  g = c*4096 + i*64 + j (flat idx per batch)
// pe_flat is the [H=64, W=64, C=256] pe tensor viewed flat (reference's raw reshape):
//   c2 = g & 255, j2 = (g >> 8) & 63, i2 = (g >> 14) & 63
//   pe = jj*(W0-W2) + ii*(W1-W3) + (W2+W3+b),   jj = j2/63, ii = i2/63
// pe is batch-independent. Grid stride = 2^20 float4 = exactly 4 batches, so each
// thread's within-batch position is loop-invariant -> pe computed once in registers.
//
// R7: single-variable vs R5 — nontemporal LOAD -> normal load, keeping the
// two-phase 8-outstanding schedule (R6 proved collapsing the schedule costs
// 20%: per-iteration vmcnt waits serialize on store-acks). Theory: regime is
// latency/MLP-bound (2.8-3.4 TB/s << 6.3 ceiling, VALUBusy 2.3%); R6's
// FETCH_SIZE=64MB shows normal loads get ~half their data from L3 at ~half
// the miss latency, which converts directly to throughput when latency-bound.
// nt loads forfeit that by bypassing cache allocation.

typedef float vf4 __attribute__((ext_vector_type(4)));

#define TOTAL_F4   (1u << 23)        // 32*256*64*64 floats / 4
#define THREADS    256
#define BLOCKS     4096              // 2^20 threads total
#define STRIDE_F4  (1u << 20)        // BLOCKS*THREADS; = 4 batches worth of float4
#define ITERS      8                 // TOTAL_F4 / STRIDE_F4

__global__ __launch_bounds__(THREADS) void pe_add_kernel(
    const float* __restrict__ x,
    const float* __restrict__ Wm,    // [256, 4] row-major
    const float* __restrict__ bias,  // [256]
    float* __restrict__ out)
{
    const unsigned t = blockIdx.x * (unsigned)THREADS + threadIdx.x;   // [0, 2^20)

    // Within-batch position (invariant across iterations).
    const unsigned p  = t & ((1u << 18) - 1u);   // float4 index within a batch
    const unsigned g  = p << 2;                  // element index within a batch
    const unsigned c2 = g & 255u;                // channel of first element (multiple of 4)
    const unsigned j2 = (g >> 8) & 63u;
    const unsigned i2 = (g >> 14) & 63u;

    const float u = (float)j2 * (1.0f / 63.0f);
    const float v = (float)i2 * (1.0f / 63.0f);

    // W rows c2 .. c2+3 and bias[c2..c2+3]: aligned 16B loads, L1/L2-hot.
    const vf4* Wrows = reinterpret_cast<const vf4*>(Wm);
    const vf4 wa = Wrows[c2 + 0];
    const vf4 wb = Wrows[c2 + 1];
    const vf4 wc = Wrows[c2 + 2];
    const vf4 wd = Wrows[c2 + 3];
    const vf4 bv = reinterpret_cast<const vf4*>(bias)[c2 >> 2];

    const vf4 pe = {
        u * (wa.x - wa.z) + v * (wa.y - wa.w) + (wa.z + wa.w + bv.x),
        u * (wb.x - wb.z) + v * (wb.y - wb.w) + (wb.z + wb.w + bv.y),
        u * (wc.x - wc.z) + v * (wc.y - wc.w) + (wc.z + wc.w + bv.z),
        u * (wd.x - wd.z) + v * (wd.y - wd.w) + (wd.z + wd.w + bv.w),
    };

    const vf4* xp = reinterpret_cast<const vf4*>(x);
    vf4*       op = reinterpret_cast<vf4*>(out);

    // Phase 1: issue all 8 loads (independent -> 8 outstanding vmem/wave).
    // Normal loads: allocate in L2/L3 path, reads half-served by L3 (~half
    // the latency of an HBM miss) per R6's FETCH_SIZE evidence.
    vf4 xv[ITERS];
#pragma unroll
    for (unsigned n = 0; n < ITERS; ++n) {
        const size_t f = (size_t)t + (size_t)n * STRIDE_F4;
        xv[n] = xp[f];
    }

    // Phase 2: add pe, store (normal store — hint proven neutral in R5).
#pragma unroll
    for (unsigned n = 0; n < ITERS; ++n) {
        const size_t f = (size_t)t + (size_t)n * STRIDE_F4;
        op[f] = xv[n] + pe;
    }
}

extern "C" void kernel_launch(void* const* d_in, const int* in_sizes, int n_in,
                              void* d_out, int out_size, void* d_ws, size_t ws_size,
                              hipStream_t stream) {
    const float* x    = (const float*)d_in[0];  // [32, 256, 64, 64] fp32
    const float* Wm   = (const float*)d_in[1];  // [256, 4] fp32
    const float* bias = (const float*)d_in[2];  // [256] fp32
    float* out = (float*)d_out;                 // [32, 256, 64, 64] fp32

    pe_add_kernel<<<dim3(BLOCKS), dim3(THREADS), 0, stream>>>(x, Wm, bias, out);
}

// Round 4
// 224.185 us; speedup vs baseline: 1.1410x; 1.0931x over previous
//
#include <hip/hip_runtime.h>
#include <hip/hip_bf16.h>

// out[b, c, i, j] = x[b, c, i, j] + pe_flat[g],  g = c*4096 + i*64 + j (flat idx per batch)
// pe_flat is the [H=64, W=64, C=256] pe tensor viewed flat (reference's raw reshape):
//   c2 = g & 255, j2 = (g >> 8) & 63, i2 = (g >> 14) & 63
//   pe = jj*(W0-W2) + ii*(W1-W3) + (W2+W3+b),   jj = j2/63, ii = i2/63
// pe is batch-independent. Stride = 2^22 float4 = exactly 16 batches, so each
// thread's within-batch position is loop-invariant -> pe computed once.
//
// R8: grid-shape probe. R4/R5 (nt loads, ITERS=8, 4096 blocks) = best at
// ~74 us kernel; R6/R7 proved per-wave MLP depth 1..8 is irrelevant and
// normal loads are 25% WORSE despite L3 serving half the reads -> limiter is
// per-request allocation cost, not latency/BW. Untested axis: grid shape.
// This round: ITERS=2, BLOCKS=16384 (4x TLP, 4x shorter wave lifetime, finer
// chip-wide read/write interleave, amortized dispatch tail). nt on BOTH loads
// and stores (R4 hints; nt-store proven neutral, keeps L2 out of the path).

typedef float vf4 __attribute__((ext_vector_type(4)));

#define TOTAL_F4   (1u << 23)        // 32*256*64*64 floats / 4
#define THREADS    256
#define BLOCKS     16384             // 2^22 threads total
#define STRIDE_F4  (1u << 22)        // BLOCKS*THREADS; = 16 batches worth of float4
#define ITERS      2                 // TOTAL_F4 / STRIDE_F4

__global__ __launch_bounds__(THREADS) void pe_add_kernel(
    const float* __restrict__ x,
    const float* __restrict__ Wm,    // [256, 4] row-major
    const float* __restrict__ bias,  // [256]
    float* __restrict__ out)
{
    const unsigned t = blockIdx.x * (unsigned)THREADS + threadIdx.x;   // [0, 2^22)

    // Within-batch position (invariant across iterations: stride = 16 batches).
    const unsigned p  = t & ((1u << 18) - 1u);   // float4 index within a batch
    const unsigned g  = p << 2;                  // element index within a batch
    const unsigned c2 = g & 255u;                // channel of first element (multiple of 4)
    const unsigned j2 = (g >> 8) & 63u;
    const unsigned i2 = (g >> 14) & 63u;

    const float u = (float)j2 * (1.0f / 63.0f);
    const float v = (float)i2 * (1.0f / 63.0f);

    // W rows c2 .. c2+3 and bias[c2..c2+3]: aligned 16B loads, L1/L2-hot.
    const vf4* Wrows = reinterpret_cast<const vf4*>(Wm);
    const vf4 wa = Wrows[c2 + 0];
    const vf4 wb = Wrows[c2 + 1];
    const vf4 wc = Wrows[c2 + 2];
    const vf4 wd = Wrows[c2 + 3];
    const vf4 bv = reinterpret_cast<const vf4*>(bias)[c2 >> 2];

    const vf4 pe = {
        u * (wa.x - wa.z) + v * (wa.y - wa.w) + (wa.z + wa.w + bv.x),
        u * (wb.x - wb.z) + v * (wb.y - wb.w) + (wb.z + wb.w + bv.y),
        u * (wc.x - wc.z) + v * (wc.y - wc.w) + (wc.z + wc.w + bv.z),
        u * (wd.x - wd.z) + v * (wd.y - wd.w) + (wd.z + wd.w + bv.w),
    };

    const vf4* xp = reinterpret_cast<const vf4*>(x);
    vf4*       op = reinterpret_cast<vf4*>(out);

    // Two-phase (both loads outstanding, then stores) with nt hints on both
    // streams — the R4 recipe, at 1/4 the per-wave burst size.
    vf4 xv[ITERS];
#pragma unroll
    for (unsigned n = 0; n < ITERS; ++n) {
        const size_t f = (size_t)t + (size_t)n * STRIDE_F4;
        xv[n] = __builtin_nontemporal_load(&xp[f]);
    }

#pragma unroll
    for (unsigned n = 0; n < ITERS; ++n) {
        const size_t f = (size_t)t + (size_t)n * STRIDE_F4;
        __builtin_nontemporal_store(xv[n] + pe, &op[f]);
    }
}

extern "C" void kernel_launch(void* const* d_in, const int* in_sizes, int n_in,
                              void* d_out, int out_size, void* d_ws, size_t ws_size,
                              hipStream_t stream) {
    const float* x    = (const float*)d_in[0];  // [32, 256, 64, 64] fp32
    const float* Wm   = (const float*)d_in[1];  // [256, 4] fp32
    const float* bias = (const float*)d_in[2];  // [256] fp32
    float* out = (float*)d_out;                 // [32, 256, 64, 64] fp32

    pe_add_kernel<<<dim3(BLOCKS), dim3(THREADS), 0, stream>>>(x, Wm, bias, out);
}